// Round 2
// baseline (36062.396 us; speedup 1.0000x reference)
//
#include <hip/hip_runtime.h>
#include <cstdint>
#include <cstddef>

// Problem constants (match reference)
#define N_ITEMS 16384
#define D_STATE 2048
#define D_SEM   1024
#define S_SLOTS 4096
#define DTHRESH 2.0f

#define B_ITEMS 256              // sequential-scan block size
#define NBLK    (N_ITEMS / B_ITEMS)   // 64
#define CHUNK_BLKS 16            // content-GEMM chunking (16 MB buffer)
#define CHUNK_ITEMS (B_ITEMS * CHUNK_BLKS)  // 4096

typedef unsigned long long u64;
typedef unsigned int u32;

// ---------------------------------------------------------------------------
// Content GEMM: C[i,j] = sum_d A[i,d]*W[j,d] + b[j].  64x64 tile, K=2048.
// ---------------------------------------------------------------------------
__global__ __launch_bounds__(256)
void gemm_kernel(const float* __restrict__ A, const float* __restrict__ W,
                 const float* __restrict__ bias, float* __restrict__ C) {
  __shared__ float As[16][68];
  __shared__ float Bs[16][68];
  const int t = threadIdx.x;
  const int ty = t >> 4, tx = t & 15;
  const int i0 = blockIdx.x * 64, j0 = blockIdx.y * 64;
  const int lrow = t >> 2, lcol = (t & 3) << 2;
  float acc[4][4] = {{0.f}};
  const float* ap = A + (size_t)(i0 + lrow) * D_STATE + lcol;
  const float* wp = W + (size_t)(j0 + lrow) * D_STATE + lcol;
  for (int k0 = 0; k0 < D_STATE; k0 += 16) {
    float4 av = *(const float4*)(ap + k0);
    float4 wv = *(const float4*)(wp + k0);
    __syncthreads();
    As[lcol + 0][lrow] = av.x; As[lcol + 1][lrow] = av.y;
    As[lcol + 2][lrow] = av.z; As[lcol + 3][lrow] = av.w;
    Bs[lcol + 0][lrow] = wv.x; Bs[lcol + 1][lrow] = wv.y;
    Bs[lcol + 2][lrow] = wv.z; Bs[lcol + 3][lrow] = wv.w;
    __syncthreads();
#pragma unroll
    for (int kk = 0; kk < 16; kk++) {
      float a[4], b[4];
#pragma unroll
      for (int y = 0; y < 4; y++) a[y] = As[kk][ty * 4 + y];
#pragma unroll
      for (int x = 0; x < 4; x++) b[x] = Bs[kk][tx * 4 + x];
#pragma unroll
      for (int y = 0; y < 4; y++)
#pragma unroll
        for (int x = 0; x < 4; x++) acc[y][x] = fmaf(a[y], b[x], acc[y][x]);
    }
  }
#pragma unroll
  for (int y = 0; y < 4; y++)
#pragma unroll
    for (int x = 0; x < 4; x++) {
      const int col = j0 + tx * 4 + x;
      C[(size_t)(i0 + ty * 4 + y) * D_SEM + col] = acc[y][x] + bias[col];
    }
}

// ---------------------------------------------------------------------------
// Per-chunk block-diagonal Gram: G[z][i][j] = c_i . c_j within block z.
// grid (4,4,CHUNK_BLKS), 64x64 tiles, K=1024.
// ---------------------------------------------------------------------------
__global__ __launch_bounds__(256)
void gram_kernel(const float* __restrict__ Cc, float* __restrict__ G) {
  const int z = blockIdx.z;
  const float* A = Cc + (size_t)z * B_ITEMS * D_SEM;
  __shared__ float As[16][68];
  __shared__ float Bs[16][68];
  const int t = threadIdx.x;
  const int ty = t >> 4, tx = t & 15;
  const int i0 = blockIdx.x * 64, j0 = blockIdx.y * 64;
  const int lrow = t >> 2, lcol = (t & 3) << 2;
  float acc[4][4] = {{0.f}};
  const float* ap = A + (size_t)(i0 + lrow) * D_SEM + lcol;
  const float* wp = A + (size_t)(j0 + lrow) * D_SEM + lcol;
  for (int k0 = 0; k0 < D_SEM; k0 += 16) {
    float4 av = *(const float4*)(ap + k0);
    float4 wv = *(const float4*)(wp + k0);
    __syncthreads();
    As[lcol + 0][lrow] = av.x; As[lcol + 1][lrow] = av.y;
    As[lcol + 2][lrow] = av.z; As[lcol + 3][lrow] = av.w;
    Bs[lcol + 0][lrow] = wv.x; Bs[lcol + 1][lrow] = wv.y;
    Bs[lcol + 2][lrow] = wv.z; Bs[lcol + 3][lrow] = wv.w;
    __syncthreads();
#pragma unroll
    for (int kk = 0; kk < 16; kk++) {
      float a[4], b[4];
#pragma unroll
      for (int y = 0; y < 4; y++) a[y] = As[kk][ty * 4 + y];
#pragma unroll
      for (int x = 0; x < 4; x++) b[x] = Bs[kk][tx * 4 + x];
#pragma unroll
      for (int y = 0; y < 4; y++)
#pragma unroll
        for (int x = 0; x < 4; x++) acc[y][x] = fmaf(a[y], b[x], acc[y][x]);
    }
  }
  float* Gz = G + (size_t)z * B_ITEMS * B_ITEMS;
#pragma unroll
  for (int y = 0; y < 4; y++)
#pragma unroll
    for (int x = 0; x < 4; x++)
      Gz[(size_t)(i0 + ty * 4 + y) * B_ITEMS + j0 + tx * 4 + x] = acc[y][x];
}

// ---------------------------------------------------------------------------
// Per-block dot-product matrix: P[i][s] = c_i . t_s.  Tiles past the
// max-possible-valid limit are zero-filled (invalid slots are masked by
// n_reg=+inf in the scan).  grid (4, 64).
// ---------------------------------------------------------------------------
__global__ __launch_bounds__(256)
void pgemm_kernel(const float* __restrict__ A,   // content block 256 x 1024
                  const float* __restrict__ T,   // traces (= out) 4096 x 1024
                  float* __restrict__ P,
                  const int* __restrict__ state) {
  const int limit = min(state[0] + B_ITEMS, S_SLOTS);
  const int j0 = blockIdx.y * 64;
  const int i0 = blockIdx.x * 64;
  const int t = threadIdx.x;
  const int ty = t >> 4, tx = t & 15;
  if (j0 >= limit) {
    const float4 z = {0.f, 0.f, 0.f, 0.f};
    const int col = j0 + tx * 4;
#pragma unroll
    for (int y = 0; y < 4; y++)
      *(float4*)(P + (size_t)(i0 + ty * 4 + y) * S_SLOTS + col) = z;
    return;
  }
  __shared__ float As[16][68];
  __shared__ float Bs[16][68];
  const int lrow = t >> 2, lcol = (t & 3) << 2;
  float acc[4][4] = {{0.f}};
  const float* ap = A + (size_t)(i0 + lrow) * D_SEM + lcol;
  const float* wp = T + (size_t)(j0 + lrow) * D_SEM + lcol;
  for (int k0 = 0; k0 < D_SEM; k0 += 16) {
    float4 av = *(const float4*)(ap + k0);
    float4 wv = *(const float4*)(wp + k0);
    __syncthreads();
    As[lcol + 0][lrow] = av.x; As[lcol + 1][lrow] = av.y;
    As[lcol + 2][lrow] = av.z; As[lcol + 3][lrow] = av.w;
    Bs[lcol + 0][lrow] = wv.x; Bs[lcol + 1][lrow] = wv.y;
    Bs[lcol + 2][lrow] = wv.z; Bs[lcol + 3][lrow] = wv.w;
    __syncthreads();
#pragma unroll
    for (int kk = 0; kk < 16; kk++) {
      float a[4], b[4];
#pragma unroll
      for (int y = 0; y < 4; y++) a[y] = As[kk][ty * 4 + y];
#pragma unroll
      for (int x = 0; x < 4; x++) b[x] = Bs[kk][tx * 4 + x];
#pragma unroll
      for (int y = 0; y < 4; y++)
#pragma unroll
        for (int x = 0; x < 4; x++) acc[y][x] = fmaf(a[y], b[x], acc[y][x]);
    }
  }
#pragma unroll
  for (int y = 0; y < 4; y++)
#pragma unroll
    for (int x = 0; x < 4; x++)
      P[(size_t)(i0 + ty * 4 + y) * S_SLOTS + j0 + tx * 4 + x] = acc[y][x];
}

// ---------------------------------------------------------------------------
// init: copy traces0 -> out (working traces), n_g[s] = ||t_s||^2, reset state.
// ---------------------------------------------------------------------------
__global__ __launch_bounds__(256)
void init_kernel(const float* __restrict__ traces0, float* __restrict__ out,
                 float* __restrict__ n_g, int* __restrict__ state) {
  __shared__ float wsum[4];
  const int s = blockIdx.x, t = threadIdx.x;
  const int lane = t & 63, wave = t >> 6;
  float4 v = *(const float4*)(traces0 + (size_t)s * D_SEM + 4 * t);
  *(float4*)(out + (size_t)s * D_SEM + 4 * t) = v;
  float nn = v.x * v.x + v.y * v.y + v.z * v.z + v.w * v.w;
#pragma unroll
  for (int o = 32; o; o >>= 1) nn += __shfl_down(nn, o, 64);
  if (lane == 0) wsum[wave] = nn;
  __syncthreads();
  if (t == 0) n_g[s] = wsum[0] + wsum[1] + wsum[2] + wsum[3];
  if (s == 0 && t == 0) { state[0] = 0; state[1] = 0; }
}

// ---------------------------------------------------------------------------
// Sequential scan, one WG, 256 thr.  Thread t owns slots [16t,16t+16) with
// P-row slices and slot norms in registers.  Deep pipeline:
//  - register window of TWO future rows (p_n1 = row i+1, p_in = row i+2);
//  - decision i fixes p_n1/p_in in-register; row i+3 gets an "entering"
//    fixup at step i+1; rows >= i+4 get a DELAYED global RMW executed at
//    step i+1, whose column read is issued at step-(i+1) TOP (address known
//    from decision i) so its latency overlaps keys/reduce/decision;
//  - post-reduce barrier waits lgkm only (global prefetches stay in flight).
// ---------------------------------------------------------------------------
__global__ __launch_bounds__(256)
void scan_kernel(float* __restrict__ P, const float* __restrict__ Gb,
                 const float* __restrict__ rewards, const float* __restrict__ n_g,
                 int* __restrict__ state, u64* __restrict__ decs) {
  __shared__ u64 partials[2][4];
  const int t = threadIdx.x;          // 0..255
  const int lane = t & 63, wave = t >> 6;
  const int s_base = t << 4;

  int num = state[0];
  int ptr = state[1];

  // per-slot ||t_s||^2 in owner registers; +inf marks invalid
  float n_reg[16];
#pragma unroll
  for (int k = 0; k < 16; k += 4) {
    float4 nv = *(const float4*)(n_g + s_base + k);
    n_reg[k + 0] = (s_base + k + 0 < num) ? nv.x : __uint_as_float(0x7F800000u);
    n_reg[k + 1] = (s_base + k + 1 < num) ? nv.y : __uint_as_float(0x7F800000u);
    n_reg[k + 2] = (s_base + k + 2 < num) ? nv.z : __uint_as_float(0x7F800000u);
    n_reg[k + 3] = (s_base + k + 3 < num) ? nv.w : __uint_as_float(0x7F800000u);
  }

  float p_cur[16], p_n1[16];
#pragma unroll
  for (int k = 0; k < 16; k += 4) {
    float4 v0 = *(const float4*)(P + s_base + k);                       // row 0
    float4 v1 = *(const float4*)(P + (size_t)S_SLOTS + s_base + k);     // row 1
    p_cur[k] = v0.x; p_cur[k + 1] = v0.y; p_cur[k + 2] = v0.z; p_cur[k + 3] = v0.w;
    p_n1[k]  = v1.x; p_n1[k + 1]  = v1.y; p_n1[k + 2]  = v1.z; p_n1[k + 3]  = v1.w;
  }

  float gi = Gb[0];          // G[i][i]
  float ri = rewards[0];

  // previous-step decision state (invalid at i=0)
  int  prev_slot = 0;
  bool prev_upd = false;
  float prev_lr = 0.f, prev_omr = 1.f;
  float greg_prev = 0.f;     // G[i-1][t]

  u32 my_slot = 0; float my_lr = 0.f;   // decision latch: thread t keeps step t

  for (int i = 0; i < B_ITEMS; i++) {
    // ---- step top: issue ALL loads (latency hidden under reduce) ----
    float p_in[16] = {0.f};
    if (i + 2 < B_ITEMS) {
      const float* rp = P + (size_t)(i + 2) * S_SLOTS + s_base;
#pragma unroll
      for (int k = 0; k < 16; k += 4) {
        float4 v = *(const float4*)(rp + k);
        p_in[k] = v.x; p_in[k + 1] = v.y; p_in[k + 2] = v.z; p_in[k + 3] = v.w;
      }
    }
    float gi_n = 0.f, ri_n = 0.f, g_ip1 = 0.f, g_ip2 = 0.f, g_prev_ip2 = 0.f;
    float greg_i = 0.f;
    if (i + 1 < B_ITEMS) {
      gi_n  = Gb[(size_t)(i + 1) * B_ITEMS + (i + 1)];
      ri_n  = rewards[i + 1];
      g_ip1 = Gb[(size_t)i * B_ITEMS + (i + 1)];
      greg_i = Gb[(size_t)i * B_ITEMS + t];      // G[i][t], for next step's RMW
    }
    if (i + 2 < B_ITEMS) {
      g_ip2 = Gb[(size_t)i * B_ITEMS + (i + 2)];
      if (i >= 1) g_prev_ip2 = Gb[(size_t)(i - 1) * B_ITEMS + (i + 2)];
    }
    // delayed-RMW read: column slot_{i-1}, rows >= i+3 (address known at top)
    const bool do_rmw = (i >= 1) && (t >= i + 3);
    float rmw_old = 0.f;
    if (do_rmw && prev_upd) rmw_old = P[(size_t)t * S_SLOTS + prev_slot];

    // ---- keys + wave reduce (argmin of n + gi - 2p; invalid => +inf) ----
    u64 best = ~0ull;
#pragma unroll
    for (int k = 0; k < 16; k++) {
      const float d2 = fmaxf(fmaf(-2.0f, p_cur[k], n_reg[k] + gi), 0.f);
      const u64 key = ((u64)__float_as_uint(d2) << 32) | (u32)(s_base + k);
      if (key < best) best = key;
    }
#pragma unroll
    for (int o = 32; o; o >>= 1) {
      const u64 v = __shfl_down(best, o, 64);
      if (v < best) best = v;
    }
    if (lane == 0) partials[i & 1][wave] = best;
    // lgkm-only barrier: keep global prefetches in flight across it
    asm volatile("s_waitcnt lgkmcnt(0)" ::: "memory");
    __builtin_amdgcn_s_barrier();
    asm volatile("" ::: "memory");

    // ---- redundant decision on every thread ----
    u64 bk = partials[i & 1][0];
    { u64 v = partials[i & 1][1]; if (v < bk) bk = v;
      v = partials[i & 1][2]; if (v < bk) bk = v;
      v = partials[i & 1][3]; if (v < bk) bk = v; }
    const float d2b = __uint_as_float((u32)(bk >> 32));
    const int nslot = (int)(u32)bk;
    const bool upd = (num > 0) && (sqrtf(d2b) < DTHRESH);
    const float lr = __fmul_rn(0.01f, __fadd_rn(1.0f, fabsf(ri)));
    const int slot = upd ? nslot : ptr;
    const float omr = 1.0f - lr;
    if (!upd) { num = min(num + 1, S_SLOTS); ptr = (ptr + 1) & (S_SLOTS - 1); }
    if (i == t) { my_slot = (u32)slot | (upd ? 0x80000000u : 0u); my_lr = lr; }

    // ---- delayed global RMW: decision i-1 applied to rows >= i+3 ----
    if (do_rmw) {
      P[(size_t)t * S_SLOTS + prev_slot] =
          prev_upd ? fmaf(prev_omr, rmw_old, __fmul_rn(prev_lr, greg_prev))
                   : greg_prev;
    }

    // ---- entering fixup: decision i-1 applied to freshly loaded row i+2 ----
    if (i >= 1 && i + 2 < B_ITEMS && (prev_slot >> 4) == t) {
#define ENT(K) { p_in[K] = prev_upd ? fmaf(prev_omr, p_in[K], __fmul_rn(prev_lr, g_prev_ip2)) : g_prev_ip2; }
      switch (prev_slot & 15) {
        case 0:  ENT(0)  break; case 1:  ENT(1)  break;
        case 2:  ENT(2)  break; case 3:  ENT(3)  break;
        case 4:  ENT(4)  break; case 5:  ENT(5)  break;
        case 6:  ENT(6)  break; case 7:  ENT(7)  break;
        case 8:  ENT(8)  break; case 9:  ENT(9)  break;
        case 10: ENT(10) break; case 11: ENT(11) break;
        case 12: ENT(12) break; case 13: ENT(13) break;
        case 14: ENT(14) break; default: ENT(15) break;
      }
#undef ENT
    }

    // ---- owner: norm recurrence + in-window fixups (rows i+1, i+2) ----
    if ((slot >> 4) == t) {
#define WFIX(K) { const float nold = n_reg[K]; float nnew; \
      if (upd) { const float pc = 0.5f * (nold + gi - d2b); \
        nnew = omr * omr * nold + 2.0f * lr * omr * pc + lr * lr * gi; \
        if (i + 1 < B_ITEMS) p_n1[K] = fmaf(omr, p_n1[K], __fmul_rn(lr, g_ip1)); \
        if (i + 2 < B_ITEMS) p_in[K] = fmaf(omr, p_in[K], __fmul_rn(lr, g_ip2)); \
      } else { nnew = gi; \
        if (i + 1 < B_ITEMS) p_n1[K] = g_ip1; \
        if (i + 2 < B_ITEMS) p_in[K] = g_ip2; } \
      n_reg[K] = nnew; }
      switch (slot & 15) {
        case 0:  WFIX(0)  break; case 1:  WFIX(1)  break;
        case 2:  WFIX(2)  break; case 3:  WFIX(3)  break;
        case 4:  WFIX(4)  break; case 5:  WFIX(5)  break;
        case 6:  WFIX(6)  break; case 7:  WFIX(7)  break;
        case 8:  WFIX(8)  break; case 9:  WFIX(9)  break;
        case 10: WFIX(10) break; case 11: WFIX(11) break;
        case 12: WFIX(12) break; case 13: WFIX(13) break;
        case 14: WFIX(14) break; default: WFIX(15) break;
      }
#undef WFIX
    }

    // ---- rotate ----
#pragma unroll
    for (int k = 0; k < 16; k++) { p_cur[k] = p_n1[k]; p_n1[k] = p_in[k]; }
    gi = gi_n; ri = ri_n;
    prev_slot = slot; prev_upd = upd; prev_lr = lr; prev_omr = omr;
    greg_prev = greg_i;
    __syncthreads();   // drains RMW store before next step's prefetch reads
  }

  if (t == 0) { state[0] = num; state[1] = ptr; }
  decs[t] = ((u64)__float_as_uint(my_lr) << 32) | (u64)my_slot;
}

// ---------------------------------------------------------------------------
// apply: materialize the block's trace mutations. WG j owns slot_j iff step j
// is the LAST step touching it. Composition: t = alpha*t_snap + sum beta_j c_j.
// Recomputes exact ||t||^2 -> n_g (bounds numeric drift to one block).
// ---------------------------------------------------------------------------
__global__ __launch_bounds__(256)
void apply_kernel(const float* __restrict__ content,  // block 256 x 1024
                  const u64* __restrict__ decs,       // 256 decisions
                  float* __restrict__ traces,         // = out
                  float* __restrict__ n_g) {
  __shared__ u32 aslot[B_ITEMS];
  __shared__ float alr[B_ITEMS];
  __shared__ float betas[B_ITEMS];
  __shared__ int notowner;
  __shared__ float wsum[4];
  const int t = threadIdx.x, j = blockIdx.x;
  const int lane = t & 63, wave = t >> 6;
  const u64 d = decs[t];
  aslot[t] = (u32)(d & 0xFFFFFFFFull);
  alr[t] = __uint_as_float((u32)(d >> 32));
  if (t == 0) notowner = 0;
  __syncthreads();
  const u32 myslot = aslot[j] & 0x7FFFFFFFu;
  if (t > j && (aslot[t] & 0x7FFFFFFFu) == myslot) notowner = 1;
  __syncthreads();
  if (notowner) return;

  float alpha = 1.f, beta = 0.f;
  for (int k = 0; k < B_ITEMS; k++) {
    const u32 a = aslot[k];
    if ((a & 0x7FFFFFFFu) == myslot) {
      const float lr = alr[k];
      if (a & 0x80000000u) {           // update
        const float om = 1.f - lr;
        alpha *= om; beta *= om;
        if (t == k) beta += lr;
      } else {                         // insert
        alpha = 0.f; beta = (t == k) ? 1.f : 0.f;
      }
    }
  }
  betas[t] = beta;
  __syncthreads();

  float4 v = *(const float4*)(traces + (size_t)myslot * D_SEM + 4 * t);
  v.x *= alpha; v.y *= alpha; v.z *= alpha; v.w *= alpha;
  for (int k = 0; k < B_ITEMS; k++) {
    if ((aslot[k] & 0x7FFFFFFFu) == myslot) {
      const float bk = betas[k];
      const float4 c = *(const float4*)(content + (size_t)k * D_SEM + 4 * t);
      v.x = fmaf(bk, c.x, v.x); v.y = fmaf(bk, c.y, v.y);
      v.z = fmaf(bk, c.z, v.z); v.w = fmaf(bk, c.w, v.w);
    }
  }
  *(float4*)(traces + (size_t)myslot * D_SEM + 4 * t) = v;
  float nn = v.x * v.x + v.y * v.y + v.z * v.z + v.w * v.w;
#pragma unroll
  for (int o = 32; o; o >>= 1) nn += __shfl_down(nn, o, 64);
  if (lane == 0) wsum[wave] = nn;
  __syncthreads();
  if (t == 0) n_g[myslot] = wsum[0] + wsum[1] + wsum[2] + wsum[3];
}

// ---------------------------------------------------------------------------
// finalize: parallel strengths replay via two-pass LDS histogram.
// Per slot: final strength = 1 + (#updates after last insert) if ever
// inserted, else strengths0 + #updates.  Then masked mean + scalars.
// ---------------------------------------------------------------------------
__global__ __launch_bounds__(256)
void finalize_kernel(const float* __restrict__ strengths0,
                     const u64* __restrict__ decs,
                     const int* __restrict__ state, float* __restrict__ out) {
  __shared__ int last_ins[S_SLOTS];
  __shared__ int cnt[S_SLOTS];
  __shared__ float wsum[4];
  const int t = threadIdx.x, lane = t & 63, wave = t >> 6;
  for (int s = t; s < S_SLOTS; s += 256) { last_ins[s] = -1; cnt[s] = 0; }
  __syncthreads();
  // pass 1: last insert index per slot
  for (int k = t; k < N_ITEMS; k += 256) {
    const u32 dd = (u32)(decs[k] & 0xFFFFFFFFull);
    if (!(dd & 0x80000000u)) atomicMax(&last_ins[(int)dd], k);
  }
  __syncthreads();
  // pass 2: count updates after the last insert
  for (int k = t; k < N_ITEMS; k += 256) {
    const u32 dd = (u32)(decs[k] & 0xFFFFFFFFull);
    const int slot = (int)(dd & 0x7FFFFFFFu);
    if ((dd & 0x80000000u) && k > last_ins[slot]) atomicAdd(&cnt[slot], 1);
  }
  __syncthreads();
  const int num = state[0];
  float* outs = out + (size_t)S_SLOTS * D_SEM;
  float lsum = 0.f;
  for (int s = t; s < S_SLOTS; s += 256) {
    const float base = (last_ins[s] >= 0) ? 1.f : strengths0[s];
    const float v = base + (float)cnt[s];
    outs[s] = v;
    if (s < num) lsum += v;
  }
#pragma unroll
  for (int o = 32; o; o >>= 1) lsum += __shfl_down(lsum, o, 64);
  if (lane == 0) wsum[wave] = lsum;
  __syncthreads();
  if (t == 0) {
    const float total = wsum[0] + wsum[1] + wsum[2] + wsum[3];
    float denom = (float)num;
    if (denom < 1.f) denom = 1.f;
    outs[S_SLOTS + 0] = (float)num;
    outs[S_SLOTS + 1] = (float)N_ITEMS;
    outs[S_SLOTS + 2] = (num > 0) ? (total / denom) : 0.f;
  }
}

// ---------------------------------------------------------------------------
extern "C" void kernel_launch(void* const* d_in, const int* in_sizes, int n_in,
                              void* d_out, int out_size, void* d_ws, size_t ws_size,
                              hipStream_t stream) {
  const float* states  = (const float*)d_in[0];
  const float* rewards = (const float*)d_in[1];
  const float* W       = (const float*)d_in[2];
  const float* bias    = (const float*)d_in[3];
  const float* traces0 = (const float*)d_in[4];
  const float* str0    = (const float*)d_in[5];
  float* out = (float*)d_out;   // traces live here (working + final)

  // ws layout (~24.5 MB): content chunk 16MB | P 4MB | Gram 4MB | n_g | decs | state
  char* p = (char*)d_ws;
  float* cbuf = (float*)p;                 p += (size_t)CHUNK_ITEMS * D_SEM * 4;
  float* P    = (float*)p;                 p += (size_t)B_ITEMS * S_SLOTS * 4;
  float* Gb   = (float*)p;                 p += (size_t)CHUNK_BLKS * B_ITEMS * B_ITEMS * 4;
  float* n_g  = (float*)p;                 p += (size_t)S_SLOTS * 4;
  u64*   decs = (u64*)p;                   p += (size_t)N_ITEMS * 8;
  int*   state = (int*)p;

  init_kernel<<<S_SLOTS, 256, 0, stream>>>(traces0, out, n_g, state);

  for (int c = 0; c < N_ITEMS / CHUNK_ITEMS; c++) {
    gemm_kernel<<<dim3(CHUNK_ITEMS / 64, D_SEM / 64), 256, 0, stream>>>(
        states + (size_t)c * CHUNK_ITEMS * D_STATE, W, bias, cbuf);
    gram_kernel<<<dim3(4, 4, CHUNK_BLKS), 256, 0, stream>>>(cbuf, Gb);
    for (int bb = 0; bb < CHUNK_BLKS; bb++) {
      const int b = c * CHUNK_BLKS + bb;
      const float* cblk = cbuf + (size_t)bb * B_ITEMS * D_SEM;
      const float* Gblk = Gb + (size_t)bb * B_ITEMS * B_ITEMS;
      pgemm_kernel<<<dim3(4, S_SLOTS / 64), 256, 0, stream>>>(cblk, out, P, state);
      scan_kernel<<<1, 256, 0, stream>>>(P, Gblk, rewards + (size_t)b * B_ITEMS,
                                         n_g, state, decs + (size_t)b * B_ITEMS);
      apply_kernel<<<B_ITEMS, 256, 0, stream>>>(cblk, decs + (size_t)b * B_ITEMS,
                                                out, n_g);
    }
  }
  finalize_kernel<<<1, 256, 0, stream>>>(str0, decs, state, out);
}

// Round 3
// 35836.075 us; speedup vs baseline: 1.0063x; 1.0063x over previous
//
#include <hip/hip_runtime.h>
#include <cstdint>
#include <cstddef>

// Problem constants (match reference)
#define N_ITEMS 16384
#define D_STATE 2048
#define D_SEM   1024
#define S_SLOTS 4096
#define DTHRESH 2.0f

#define B_ITEMS 256              // sequential-scan block size
#define NBLK    (N_ITEMS / B_ITEMS)   // 64
#define CHUNK_BLKS 16            // content-GEMM chunking (16 MB buffer)
#define CHUNK_ITEMS (B_ITEMS * CHUNK_BLKS)  // 4096

typedef unsigned long long u64;
typedef unsigned int u32;

// ---------------------------------------------------------------------------
// Content GEMM: C[i,j] = sum_d A[i,d]*W[j,d] + b[j].  64x64 tile, K=2048.
// ---------------------------------------------------------------------------
__global__ __launch_bounds__(256)
void gemm_kernel(const float* __restrict__ A, const float* __restrict__ W,
                 const float* __restrict__ bias, float* __restrict__ C) {
  __shared__ float As[16][68];
  __shared__ float Bs[16][68];
  const int t = threadIdx.x;
  const int ty = t >> 4, tx = t & 15;
  const int i0 = blockIdx.x * 64, j0 = blockIdx.y * 64;
  const int lrow = t >> 2, lcol = (t & 3) << 2;
  float acc[4][4] = {{0.f}};
  const float* ap = A + (size_t)(i0 + lrow) * D_STATE + lcol;
  const float* wp = W + (size_t)(j0 + lrow) * D_STATE + lcol;
  for (int k0 = 0; k0 < D_STATE; k0 += 16) {
    float4 av = *(const float4*)(ap + k0);
    float4 wv = *(const float4*)(wp + k0);
    __syncthreads();
    As[lcol + 0][lrow] = av.x; As[lcol + 1][lrow] = av.y;
    As[lcol + 2][lrow] = av.z; As[lcol + 3][lrow] = av.w;
    Bs[lcol + 0][lrow] = wv.x; Bs[lcol + 1][lrow] = wv.y;
    Bs[lcol + 2][lrow] = wv.z; Bs[lcol + 3][lrow] = wv.w;
    __syncthreads();
#pragma unroll
    for (int kk = 0; kk < 16; kk++) {
      float a[4], b[4];
#pragma unroll
      for (int y = 0; y < 4; y++) a[y] = As[kk][ty * 4 + y];
#pragma unroll
      for (int x = 0; x < 4; x++) b[x] = Bs[kk][tx * 4 + x];
#pragma unroll
      for (int y = 0; y < 4; y++)
#pragma unroll
        for (int x = 0; x < 4; x++) acc[y][x] = fmaf(a[y], b[x], acc[y][x]);
    }
  }
#pragma unroll
  for (int y = 0; y < 4; y++)
#pragma unroll
    for (int x = 0; x < 4; x++) {
      const int col = j0 + tx * 4 + x;
      C[(size_t)(i0 + ty * 4 + y) * D_SEM + col] = acc[y][x] + bias[col];
    }
}

// ---------------------------------------------------------------------------
// Per-chunk block-diagonal Gram: G[z][i][j] = c_i . c_j within block z.
// grid (4,4,CHUNK_BLKS), 64x64 tiles, K=1024.
// ---------------------------------------------------------------------------
__global__ __launch_bounds__(256)
void gram_kernel(const float* __restrict__ Cc, float* __restrict__ G) {
  const int z = blockIdx.z;
  const float* A = Cc + (size_t)z * B_ITEMS * D_SEM;
  __shared__ float As[16][68];
  __shared__ float Bs[16][68];
  const int t = threadIdx.x;
  const int ty = t >> 4, tx = t & 15;
  const int i0 = blockIdx.x * 64, j0 = blockIdx.y * 64;
  const int lrow = t >> 2, lcol = (t & 3) << 2;
  float acc[4][4] = {{0.f}};
  const float* ap = A + (size_t)(i0 + lrow) * D_SEM + lcol;
  const float* wp = A + (size_t)(j0 + lrow) * D_SEM + lcol;
  for (int k0 = 0; k0 < D_SEM; k0 += 16) {
    float4 av = *(const float4*)(ap + k0);
    float4 wv = *(const float4*)(wp + k0);
    __syncthreads();
    As[lcol + 0][lrow] = av.x; As[lcol + 1][lrow] = av.y;
    As[lcol + 2][lrow] = av.z; As[lcol + 3][lrow] = av.w;
    Bs[lcol + 0][lrow] = wv.x; Bs[lcol + 1][lrow] = wv.y;
    Bs[lcol + 2][lrow] = wv.z; Bs[lcol + 3][lrow] = wv.w;
    __syncthreads();
#pragma unroll
    for (int kk = 0; kk < 16; kk++) {
      float a[4], b[4];
#pragma unroll
      for (int y = 0; y < 4; y++) a[y] = As[kk][ty * 4 + y];
#pragma unroll
      for (int x = 0; x < 4; x++) b[x] = Bs[kk][tx * 4 + x];
#pragma unroll
      for (int y = 0; y < 4; y++)
#pragma unroll
        for (int x = 0; x < 4; x++) acc[y][x] = fmaf(a[y], b[x], acc[y][x]);
    }
  }
  float* Gz = G + (size_t)z * B_ITEMS * B_ITEMS;
#pragma unroll
  for (int y = 0; y < 4; y++)
#pragma unroll
    for (int x = 0; x < 4; x++)
      Gz[(size_t)(i0 + ty * 4 + y) * B_ITEMS + j0 + tx * 4 + x] = acc[y][x];
}

// ---------------------------------------------------------------------------
// Per-block dot-product matrix: P0[i][s] = c_i . t_s(block start).  Read-only
// in the scan.  Tiles past the max-possible-valid limit are zero-filled
// (finite; invalid slots are masked by n_reg=+inf in the scan).  grid (4,64).
// ---------------------------------------------------------------------------
__global__ __launch_bounds__(256)
void pgemm_kernel(const float* __restrict__ A,   // content block 256 x 1024
                  const float* __restrict__ T,   // traces (= out) 4096 x 1024
                  float* __restrict__ P,
                  const int* __restrict__ state) {
  const int limit = min(state[0] + B_ITEMS, S_SLOTS);
  const int j0 = blockIdx.y * 64;
  const int i0 = blockIdx.x * 64;
  const int t = threadIdx.x;
  const int ty = t >> 4, tx = t & 15;
  if (j0 >= limit) {
    const float4 z = {0.f, 0.f, 0.f, 0.f};
    const int col = j0 + tx * 4;
#pragma unroll
    for (int y = 0; y < 4; y++)
      *(float4*)(P + (size_t)(i0 + ty * 4 + y) * S_SLOTS + col) = z;
    return;
  }
  __shared__ float As[16][68];
  __shared__ float Bs[16][68];
  const int lrow = t >> 2, lcol = (t & 3) << 2;
  float acc[4][4] = {{0.f}};
  const float* ap = A + (size_t)(i0 + lrow) * D_SEM + lcol;
  const float* wp = T + (size_t)(j0 + lrow) * D_SEM + lcol;
  for (int k0 = 0; k0 < D_SEM; k0 += 16) {
    float4 av = *(const float4*)(ap + k0);
    float4 wv = *(const float4*)(wp + k0);
    __syncthreads();
    As[lcol + 0][lrow] = av.x; As[lcol + 1][lrow] = av.y;
    As[lcol + 2][lrow] = av.z; As[lcol + 3][lrow] = av.w;
    Bs[lcol + 0][lrow] = wv.x; Bs[lcol + 1][lrow] = wv.y;
    Bs[lcol + 2][lrow] = wv.z; Bs[lcol + 3][lrow] = wv.w;
    __syncthreads();
#pragma unroll
    for (int kk = 0; kk < 16; kk++) {
      float a[4], b[4];
#pragma unroll
      for (int y = 0; y < 4; y++) a[y] = As[kk][ty * 4 + y];
#pragma unroll
      for (int x = 0; x < 4; x++) b[x] = Bs[kk][tx * 4 + x];
#pragma unroll
      for (int y = 0; y < 4; y++)
#pragma unroll
        for (int x = 0; x < 4; x++) acc[y][x] = fmaf(a[y], b[x], acc[y][x]);
    }
  }
#pragma unroll
  for (int y = 0; y < 4; y++)
#pragma unroll
    for (int x = 0; x < 4; x++)
      P[(size_t)(i0 + ty * 4 + y) * S_SLOTS + j0 + tx * 4 + x] = acc[y][x];
}

// ---------------------------------------------------------------------------
// init: copy traces0 -> out (working traces), n_g[s] = ||t_s||^2, reset state.
// ---------------------------------------------------------------------------
__global__ __launch_bounds__(256)
void init_kernel(const float* __restrict__ traces0, float* __restrict__ out,
                 float* __restrict__ n_g, int* __restrict__ state) {
  __shared__ float wsum[4];
  const int s = blockIdx.x, t = threadIdx.x;
  const int lane = t & 63, wave = t >> 6;
  float4 v = *(const float4*)(traces0 + (size_t)s * D_SEM + 4 * t);
  *(float4*)(out + (size_t)s * D_SEM + 4 * t) = v;
  float nn = v.x * v.x + v.y * v.y + v.z * v.z + v.w * v.w;
#pragma unroll
  for (int o = 32; o; o >>= 1) nn += __shfl_down(nn, o, 64);
  if (lane == 0) wsum[wave] = nn;
  __syncthreads();
  if (t == 0) n_g[s] = wsum[0] + wsum[1] + wsum[2] + wsum[3];
  if (s == 0 && t == 0) { state[0] = 0; state[1] = 0; }
}

// ---------------------------------------------------------------------------
// Sequential scan, one WG, 256 thr.  Thread t owns slots [16t,16t+16).
// P0 is READ-ONLY: trace evolution is tracked as t_s = alpha_s*t_s0 +
// sum_j coeff_j*c_j.  Thread j keeps its own decision entry (my_cslot,
// my_coeff) in registers; an entering row r gets its correction via a tiny
// LDS atomicAdd scatter of coeff_j * G[r][j] (coalesced G row read), applied
// once at entry: p = alpha*P0_raw + corr.  NO global stores in the loop ->
// lgkm-only barriers; global prefetches (2-step lead, ping-pong reg buffers)
// stay in flight across steps.
// ---------------------------------------------------------------------------
__global__ __launch_bounds__(256, 1)
void scan_kernel(const float* __restrict__ P, const float* __restrict__ Gb,
                 const float* __restrict__ rewards, const float* __restrict__ n_g,
                 int* __restrict__ state, u64* __restrict__ decs) {
  __shared__ float corr_buf[S_SLOTS];   // per-entering-row corrections (16KB)
  __shared__ u64 partials[4];
  const int t = threadIdx.x;          // 0..255
  const int lane = t & 63, wave = t >> 6;
  const int s_base = t << 4;

  int num = state[0];
  int ptr = state[1];

  for (int s = t; s < S_SLOTS; s += 256) corr_buf[s] = 0.f;

  // per-slot ||t_s||^2 in owner registers; +inf marks invalid
  float n_reg[16];
#pragma unroll
  for (int k = 0; k < 16; k += 4) {
    float4 nv = *(const float4*)(n_g + s_base + k);
    n_reg[k + 0] = (s_base + k + 0 < num) ? nv.x : __uint_as_float(0x7F800000u);
    n_reg[k + 1] = (s_base + k + 1 < num) ? nv.y : __uint_as_float(0x7F800000u);
    n_reg[k + 2] = (s_base + k + 2 < num) ? nv.z : __uint_as_float(0x7F800000u);
    n_reg[k + 3] = (s_base + k + 3 < num) ? nv.w : __uint_as_float(0x7F800000u);
  }
  float alpha_r[16];
#pragma unroll
  for (int k = 0; k < 16; k++) alpha_r[k] = 1.f;

  // window: p_cur = row i, p_n1 = row i+1 (both fully corrected)
  float p_cur[16], p_n1[16], p_in[16];
#pragma unroll
  for (int k = 0; k < 16; k += 4) {
    float4 v0 = *(const float4*)(P + s_base + k);                       // row 0
    float4 v1 = *(const float4*)(P + (size_t)S_SLOTS + s_base + k);     // row 1
    p_cur[k] = v0.x; p_cur[k + 1] = v0.y; p_cur[k + 2] = v0.z; p_cur[k + 3] = v0.w;
    p_n1[k]  = v1.x; p_n1[k + 1]  = v1.y; p_n1[k + 2]  = v1.z; p_n1[k + 3]  = v1.w;
  }
#pragma unroll
  for (int k = 0; k < 16; k++) p_in[k] = 0.f;

  // raw prefetch ping-pong: buffer A holds row 2 initially
  float p_raw_a[16], p_raw_b[16];
  float gc_a, gc_b;
  {
    const float* rp = P + (size_t)2 * S_SLOTS + s_base;
#pragma unroll
    for (int k = 0; k < 16; k += 4) {
      float4 v = *(const float4*)(rp + k);
      p_raw_a[k] = v.x; p_raw_a[k + 1] = v.y; p_raw_a[k + 2] = v.z; p_raw_a[k + 3] = v.w;
    }
    gc_a = Gb[(size_t)2 * B_ITEMS + t];
    gc_b = 0.f;
#pragma unroll
    for (int k = 0; k < 16; k++) p_raw_b[k] = 0.f;
  }

  float gi = Gb[0];          // G[i][i]
  float ri = rewards[0];
  float g1 = Gb[1];          // G[i][i+1]

  int my_cslot = -1; float my_coeff = 0.f;   // thread t's decision entry
  u32 my_slot = 0; float my_lr = 0.f;        // decision latch for decs[]

  __syncthreads();   // corr_buf zero + prologue visible

#define OWNFIX(K, I) { const float nold = n_reg[K]; \
    if (upd) { const float pc = 0.5f * (nold + gi - d2b); \
      n_reg[K] = omr * omr * nold + 2.0f * lr * omr * pc + lr * lr * gi; \
      alpha_r[K] = __fmul_rn(alpha_r[K], omr); \
      if ((I) + 1 < B_ITEMS) p_n1[K] = fmaf(omr, p_n1[K], __fmul_rn(lr, g1)); \
    } else { n_reg[K] = gi; alpha_r[K] = 0.f; \
      if ((I) + 1 < B_ITEMS) p_n1[K] = g1; } }

#define SCAN_STEP(I, RAWC, GCC, RAWN, GCN) { \
    /* TOP: issue prefetches for row I+3 and next-step scalars */ \
    if ((I) + 3 < B_ITEMS) { \
      const float* rp = P + (size_t)((I) + 3) * S_SLOTS + s_base; \
      _Pragma("unroll") \
      for (int k = 0; k < 16; k += 4) { \
        float4 v = *(const float4*)(rp + k); \
        RAWN[k] = v.x; RAWN[k + 1] = v.y; RAWN[k + 2] = v.z; RAWN[k + 3] = v.w; \
      } \
      GCN = Gb[(size_t)((I) + 3) * B_ITEMS + t]; \
    } \
    float gi_n = 0.f, ri_n = 0.f, g1_n = 0.f; \
    if ((I) + 1 < B_ITEMS) { \
      gi_n = Gb[(size_t)((I) + 1) * B_ITEMS + (I) + 1]; \
      ri_n = rewards[(I) + 1]; \
      if ((I) + 2 < B_ITEMS) g1_n = Gb[(size_t)((I) + 1) * B_ITEMS + (I) + 2]; \
    } \
    /* KEYS + wave reduce */ \
    u64 best = ~0ull; \
    _Pragma("unroll") \
    for (int k = 0; k < 16; k++) { \
      const float d2 = fmaxf(fmaf(-2.0f, p_cur[k], n_reg[k] + gi), 0.f); \
      const u64 key = ((u64)__float_as_uint(d2) << 32) | (u32)(s_base + k); \
      if (key < best) best = key; \
    } \
    _Pragma("unroll") \
    for (int o = 32; o; o >>= 1) { \
      const u64 v = __shfl_down(best, o, 64); \
      if (v < best) best = v; \
    } \
    if (lane == 0) partials[wave] = best; \
    asm volatile("s_waitcnt lgkmcnt(0)" ::: "memory"); \
    __builtin_amdgcn_s_barrier(); \
    __builtin_amdgcn_sched_barrier(0); \
    /* DEC: redundant decision on every thread */ \
    u64 bk = partials[0]; \
    { u64 v = partials[1]; if (v < bk) bk = v; \
      v = partials[2]; if (v < bk) bk = v; \
      v = partials[3]; if (v < bk) bk = v; } \
    const float d2b = __uint_as_float((u32)(bk >> 32)); \
    const int nslot = (int)(u32)bk; \
    const bool upd = (num > 0) && (d2b < 4.0f); \
    const float lr = __fmul_rn(0.01f, __fadd_rn(1.0f, fabsf(ri))); \
    const int slot = upd ? nslot : ptr; \
    const float omr = 1.0f - lr; \
    if (!upd) { num = min(num + 1, S_SLOTS); ptr = (ptr + 1) & (S_SLOTS - 1); } \
    if ((I) == t) { my_slot = (u32)slot | (upd ? 0x80000000u : 0u); my_lr = lr; } \
    if (my_cslot == slot) my_coeff = upd ? __fmul_rn(my_coeff, omr) : 0.f; \
    if ((I) == t) { my_cslot = slot; my_coeff = upd ? lr : 1.f; } \
    if ((slot >> 4) == t) { \
      switch (slot & 15) { \
        case 0:  OWNFIX(0,  I) break; case 1:  OWNFIX(1,  I) break; \
        case 2:  OWNFIX(2,  I) break; case 3:  OWNFIX(3,  I) break; \
        case 4:  OWNFIX(4,  I) break; case 5:  OWNFIX(5,  I) break; \
        case 6:  OWNFIX(6,  I) break; case 7:  OWNFIX(7,  I) break; \
        case 8:  OWNFIX(8,  I) break; case 9:  OWNFIX(9,  I) break; \
        case 10: OWNFIX(10, I) break; case 11: OWNFIX(11, I) break; \
        case 12: OWNFIX(12, I) break; case 13: OWNFIX(13, I) break; \
        case 14: OWNFIX(14, I) break; default: OWNFIX(15, I) break; \
      } \
    } \
    /* CORR: scatter coeff_j * G[I+2][j] for entering row */ \
    if ((I) + 2 < B_ITEMS && my_coeff != 0.f) \
      atomicAdd(&corr_buf[my_cslot], __fmul_rn(my_coeff, GCC)); \
    asm volatile("s_waitcnt lgkmcnt(0)" ::: "memory"); \
    __builtin_amdgcn_s_barrier(); \
    __builtin_amdgcn_sched_barrier(0); \
    /* APPLY entering row I+2: p = alpha*P0_raw + corr; zero corr */ \
    if ((I) + 2 < B_ITEMS) { \
      const float4 z4 = {0.f, 0.f, 0.f, 0.f}; \
      _Pragma("unroll") \
      for (int k = 0; k < 16; k += 4) { \
        float4 cv = *(const float4*)(&corr_buf[s_base + k]); \
        p_in[k + 0] = fmaf(alpha_r[k + 0], RAWC[k + 0], cv.x); \
        p_in[k + 1] = fmaf(alpha_r[k + 1], RAWC[k + 1], cv.y); \
        p_in[k + 2] = fmaf(alpha_r[k + 2], RAWC[k + 2], cv.z); \
        p_in[k + 3] = fmaf(alpha_r[k + 3], RAWC[k + 3], cv.w); \
        *(float4*)(&corr_buf[s_base + k]) = z4; \
      } \
    } \
    /* ROT */ \
    _Pragma("unroll") \
    for (int k = 0; k < 16; k++) { p_cur[k] = p_n1[k]; p_n1[k] = p_in[k]; } \
    gi = gi_n; ri = ri_n; g1 = g1_n; \
  }

  for (int i = 0; i < B_ITEMS; i += 2) {
    SCAN_STEP(i,     p_raw_a, gc_a, p_raw_b, gc_b)
    SCAN_STEP(i + 1, p_raw_b, gc_b, p_raw_a, gc_a)
  }
#undef SCAN_STEP
#undef OWNFIX

  if (t == 0) { state[0] = num; state[1] = ptr; }
  decs[t] = ((u64)__float_as_uint(my_lr) << 32) | (u64)my_slot;
}

// ---------------------------------------------------------------------------
// apply: materialize the block's trace mutations. WG j owns slot_j iff step j
// is the LAST step touching it. Composition: t = alpha*t_snap + sum beta_j c_j.
// Recomputes exact ||t||^2 -> n_g (bounds numeric drift to one block).
// ---------------------------------------------------------------------------
__global__ __launch_bounds__(256)
void apply_kernel(const float* __restrict__ content,  // block 256 x 1024
                  const u64* __restrict__ decs,       // 256 decisions
                  float* __restrict__ traces,         // = out
                  float* __restrict__ n_g) {
  __shared__ u32 aslot[B_ITEMS];
  __shared__ float alr[B_ITEMS];
  __shared__ float betas[B_ITEMS];
  __shared__ int notowner;
  __shared__ float wsum[4];
  const int t = threadIdx.x, j = blockIdx.x;
  const int lane = t & 63, wave = t >> 6;
  const u64 d = decs[t];
  aslot[t] = (u32)(d & 0xFFFFFFFFull);
  alr[t] = __uint_as_float((u32)(d >> 32));
  if (t == 0) notowner = 0;
  __syncthreads();
  const u32 myslot = aslot[j] & 0x7FFFFFFFu;
  if (t > j && (aslot[t] & 0x7FFFFFFFu) == myslot) notowner = 1;
  __syncthreads();
  if (notowner) return;

  float alpha = 1.f, beta = 0.f;
  for (int k = 0; k < B_ITEMS; k++) {
    const u32 a = aslot[k];
    if ((a & 0x7FFFFFFFu) == myslot) {
      const float lr = alr[k];
      if (a & 0x80000000u) {           // update
        const float om = 1.f - lr;
        alpha *= om; beta *= om;
        if (t == k) beta += lr;
      } else {                         // insert
        alpha = 0.f; beta = (t == k) ? 1.f : 0.f;
      }
    }
  }
  betas[t] = beta;
  __syncthreads();

  float4 v = *(const float4*)(traces + (size_t)myslot * D_SEM + 4 * t);
  v.x *= alpha; v.y *= alpha; v.z *= alpha; v.w *= alpha;
  for (int k = 0; k < B_ITEMS; k++) {
    if ((aslot[k] & 0x7FFFFFFFu) == myslot) {
      const float bk = betas[k];
      const float4 c = *(const float4*)(content + (size_t)k * D_SEM + 4 * t);
      v.x = fmaf(bk, c.x, v.x); v.y = fmaf(bk, c.y, v.y);
      v.z = fmaf(bk, c.z, v.z); v.w = fmaf(bk, c.w, v.w);
    }
  }
  *(float4*)(traces + (size_t)myslot * D_SEM + 4 * t) = v;
  float nn = v.x * v.x + v.y * v.y + v.z * v.z + v.w * v.w;
#pragma unroll
  for (int o = 32; o; o >>= 1) nn += __shfl_down(nn, o, 64);
  if (lane == 0) wsum[wave] = nn;
  __syncthreads();
  if (t == 0) n_g[myslot] = wsum[0] + wsum[1] + wsum[2] + wsum[3];
}

// ---------------------------------------------------------------------------
// finalize: parallel strengths replay via two-pass LDS histogram.
// Per slot: final strength = 1 + (#updates after last insert) if ever
// inserted, else strengths0 + #updates.  Then masked mean + scalars.
// ---------------------------------------------------------------------------
__global__ __launch_bounds__(256)
void finalize_kernel(const float* __restrict__ strengths0,
                     const u64* __restrict__ decs,
                     const int* __restrict__ state, float* __restrict__ out) {
  __shared__ int last_ins[S_SLOTS];
  __shared__ int cnt[S_SLOTS];
  __shared__ float wsum[4];
  const int t = threadIdx.x, lane = t & 63, wave = t >> 6;
  for (int s = t; s < S_SLOTS; s += 256) { last_ins[s] = -1; cnt[s] = 0; }
  __syncthreads();
  // pass 1: last insert index per slot
  for (int k = t; k < N_ITEMS; k += 256) {
    const u32 dd = (u32)(decs[k] & 0xFFFFFFFFull);
    if (!(dd & 0x80000000u)) atomicMax(&last_ins[(int)dd], k);
  }
  __syncthreads();
  // pass 2: count updates after the last insert
  for (int k = t; k < N_ITEMS; k += 256) {
    const u32 dd = (u32)(decs[k] & 0xFFFFFFFFull);
    const int slot = (int)(dd & 0x7FFFFFFFu);
    if ((dd & 0x80000000u) && k > last_ins[slot]) atomicAdd(&cnt[slot], 1);
  }
  __syncthreads();
  const int num = state[0];
  float* outs = out + (size_t)S_SLOTS * D_SEM;
  float lsum = 0.f;
  for (int s = t; s < S_SLOTS; s += 256) {
    const float base = (last_ins[s] >= 0) ? 1.f : strengths0[s];
    const float v = base + (float)cnt[s];
    outs[s] = v;
    if (s < num) lsum += v;
  }
#pragma unroll
  for (int o = 32; o; o >>= 1) lsum += __shfl_down(lsum, o, 64);
  if (lane == 0) wsum[wave] = lsum;
  __syncthreads();
  if (t == 0) {
    const float total = wsum[0] + wsum[1] + wsum[2] + wsum[3];
    float denom = (float)num;
    if (denom < 1.f) denom = 1.f;
    outs[S_SLOTS + 0] = (float)num;
    outs[S_SLOTS + 1] = (float)N_ITEMS;
    outs[S_SLOTS + 2] = (num > 0) ? (total / denom) : 0.f;
  }
}

// ---------------------------------------------------------------------------
extern "C" void kernel_launch(void* const* d_in, const int* in_sizes, int n_in,
                              void* d_out, int out_size, void* d_ws, size_t ws_size,
                              hipStream_t stream) {
  const float* states  = (const float*)d_in[0];
  const float* rewards = (const float*)d_in[1];
  const float* W       = (const float*)d_in[2];
  const float* bias    = (const float*)d_in[3];
  const float* traces0 = (const float*)d_in[4];
  const float* str0    = (const float*)d_in[5];
  float* out = (float*)d_out;   // traces live here (working + final)

  // ws layout (~24.5 MB): content chunk 16MB | P 4MB | Gram 4MB | n_g | decs | state
  char* p = (char*)d_ws;
  float* cbuf = (float*)p;                 p += (size_t)CHUNK_ITEMS * D_SEM * 4;
  float* P    = (float*)p;                 p += (size_t)B_ITEMS * S_SLOTS * 4;
  float* Gb   = (float*)p;                 p += (size_t)CHUNK_BLKS * B_ITEMS * B_ITEMS * 4;
  float* n_g  = (float*)p;                 p += (size_t)S_SLOTS * 4;
  u64*   decs = (u64*)p;                   p += (size_t)N_ITEMS * 8;
  int*   state = (int*)p;

  init_kernel<<<S_SLOTS, 256, 0, stream>>>(traces0, out, n_g, state);

  for (int c = 0; c < N_ITEMS / CHUNK_ITEMS; c++) {
    gemm_kernel<<<dim3(CHUNK_ITEMS / 64, D_SEM / 64), 256, 0, stream>>>(
        states + (size_t)c * CHUNK_ITEMS * D_STATE, W, bias, cbuf);
    gram_kernel<<<dim3(4, 4, CHUNK_BLKS), 256, 0, stream>>>(cbuf, Gb);
    for (int bb = 0; bb < CHUNK_BLKS; bb++) {
      const int b = c * CHUNK_BLKS + bb;
      const float* cblk = cbuf + (size_t)bb * B_ITEMS * D_SEM;
      const float* Gblk = Gb + (size_t)bb * B_ITEMS * B_ITEMS;
      pgemm_kernel<<<dim3(4, S_SLOTS / 64), 256, 0, stream>>>(cblk, out, P, state);
      scan_kernel<<<1, 256, 0, stream>>>(P, Gblk, rewards + (size_t)b * B_ITEMS,
                                         n_g, state, decs + (size_t)b * B_ITEMS);
      apply_kernel<<<B_ITEMS, 256, 0, stream>>>(cblk, decs + (size_t)b * B_ITEMS,
                                                out, n_g);
    }
  }
  finalize_kernel<<<1, 256, 0, stream>>>(str0, decs, state, out);
}

// Round 4
// 32263.541 us; speedup vs baseline: 1.1177x; 1.1107x over previous
//
#include <hip/hip_runtime.h>
#include <cstdint>
#include <cstddef>

// Problem constants (match reference)
#define N_ITEMS 16384
#define D_STATE 2048
#define D_SEM   1024
#define S_SLOTS 4096
#define DTHRESH 2.0f

#define B_ITEMS 256              // sequential-scan block size
#define NBLK    (N_ITEMS / B_ITEMS)   // 64
#define CHUNK_BLKS 16            // content-GEMM chunking (16 MB buffer)
#define CHUNK_ITEMS (B_ITEMS * CHUNK_BLKS)  // 4096

typedef unsigned long long u64;
typedef unsigned int u32;

// ---------------------------------------------------------------------------
// Content GEMM: C[i,j] = sum_d A[i,d]*W[j,d] + b[j].  64x64 tile, K=2048.
// ---------------------------------------------------------------------------
__global__ __launch_bounds__(256)
void gemm_kernel(const float* __restrict__ A, const float* __restrict__ W,
                 const float* __restrict__ bias, float* __restrict__ C) {
  __shared__ float As[16][68];
  __shared__ float Bs[16][68];
  const int t = threadIdx.x;
  const int ty = t >> 4, tx = t & 15;
  const int i0 = blockIdx.x * 64, j0 = blockIdx.y * 64;
  const int lrow = t >> 2, lcol = (t & 3) << 2;
  float acc[4][4] = {{0.f}};
  const float* ap = A + (size_t)(i0 + lrow) * D_STATE + lcol;
  const float* wp = W + (size_t)(j0 + lrow) * D_STATE + lcol;
  for (int k0 = 0; k0 < D_STATE; k0 += 16) {
    float4 av = *(const float4*)(ap + k0);
    float4 wv = *(const float4*)(wp + k0);
    __syncthreads();
    As[lcol + 0][lrow] = av.x; As[lcol + 1][lrow] = av.y;
    As[lcol + 2][lrow] = av.z; As[lcol + 3][lrow] = av.w;
    Bs[lcol + 0][lrow] = wv.x; Bs[lcol + 1][lrow] = wv.y;
    Bs[lcol + 2][lrow] = wv.z; Bs[lcol + 3][lrow] = wv.w;
    __syncthreads();
#pragma unroll
    for (int kk = 0; kk < 16; kk++) {
      float a[4], b[4];
#pragma unroll
      for (int y = 0; y < 4; y++) a[y] = As[kk][ty * 4 + y];
#pragma unroll
      for (int x = 0; x < 4; x++) b[x] = Bs[kk][tx * 4 + x];
#pragma unroll
      for (int y = 0; y < 4; y++)
#pragma unroll
        for (int x = 0; x < 4; x++) acc[y][x] = fmaf(a[y], b[x], acc[y][x]);
    }
  }
#pragma unroll
  for (int y = 0; y < 4; y++)
#pragma unroll
    for (int x = 0; x < 4; x++) {
      const int col = j0 + tx * 4 + x;
      C[(size_t)(i0 + ty * 4 + y) * D_SEM + col] = acc[y][x] + bias[col];
    }
}

// ---------------------------------------------------------------------------
// Per-chunk block-diagonal Gram: G[z][i][j] = c_i . c_j within block z.
// grid (4,4,CHUNK_BLKS), 64x64 tiles, K=1024.
// ---------------------------------------------------------------------------
__global__ __launch_bounds__(256)
void gram_kernel(const float* __restrict__ Cc, float* __restrict__ G) {
  const int z = blockIdx.z;
  const float* A = Cc + (size_t)z * B_ITEMS * D_SEM;
  __shared__ float As[16][68];
  __shared__ float Bs[16][68];
  const int t = threadIdx.x;
  const int ty = t >> 4, tx = t & 15;
  const int i0 = blockIdx.x * 64, j0 = blockIdx.y * 64;
  const int lrow = t >> 2, lcol = (t & 3) << 2;
  float acc[4][4] = {{0.f}};
  const float* ap = A + (size_t)(i0 + lrow) * D_SEM + lcol;
  const float* wp = A + (size_t)(j0 + lrow) * D_SEM + lcol;
  for (int k0 = 0; k0 < D_SEM; k0 += 16) {
    float4 av = *(const float4*)(ap + k0);
    float4 wv = *(const float4*)(wp + k0);
    __syncthreads();
    As[lcol + 0][lrow] = av.x; As[lcol + 1][lrow] = av.y;
    As[lcol + 2][lrow] = av.z; As[lcol + 3][lrow] = av.w;
    Bs[lcol + 0][lrow] = wv.x; Bs[lcol + 1][lrow] = wv.y;
    Bs[lcol + 2][lrow] = wv.z; Bs[lcol + 3][lrow] = wv.w;
    __syncthreads();
#pragma unroll
    for (int kk = 0; kk < 16; kk++) {
      float a[4], b[4];
#pragma unroll
      for (int y = 0; y < 4; y++) a[y] = As[kk][ty * 4 + y];
#pragma unroll
      for (int x = 0; x < 4; x++) b[x] = Bs[kk][tx * 4 + x];
#pragma unroll
      for (int y = 0; y < 4; y++)
#pragma unroll
        for (int x = 0; x < 4; x++) acc[y][x] = fmaf(a[y], b[x], acc[y][x]);
    }
  }
  float* Gz = G + (size_t)z * B_ITEMS * B_ITEMS;
#pragma unroll
  for (int y = 0; y < 4; y++)
#pragma unroll
    for (int x = 0; x < 4; x++)
      Gz[(size_t)(i0 + ty * 4 + y) * B_ITEMS + j0 + tx * 4 + x] = acc[y][x];
}

// ---------------------------------------------------------------------------
// Per-block dot-product matrix: P0[i][s] = c_i . t_s(block start).  Read-only
// in the scan.  Tiles past the max-possible-valid limit are zero-filled
// (finite; invalid slots are masked by n_reg=+inf in the scan).  grid (4,64).
// ---------------------------------------------------------------------------
__global__ __launch_bounds__(256)
void pgemm_kernel(const float* __restrict__ A,   // content block 256 x 1024
                  const float* __restrict__ T,   // traces (= out) 4096 x 1024
                  float* __restrict__ P,
                  const int* __restrict__ state) {
  const int limit = min(state[0] + B_ITEMS, S_SLOTS);
  const int j0 = blockIdx.y * 64;
  const int i0 = blockIdx.x * 64;
  const int t = threadIdx.x;
  const int ty = t >> 4, tx = t & 15;
  if (j0 >= limit) {
    const float4 z = {0.f, 0.f, 0.f, 0.f};
    const int col = j0 + tx * 4;
#pragma unroll
    for (int y = 0; y < 4; y++)
      *(float4*)(P + (size_t)(i0 + ty * 4 + y) * S_SLOTS + col) = z;
    return;
  }
  __shared__ float As[16][68];
  __shared__ float Bs[16][68];
  const int lrow = t >> 2, lcol = (t & 3) << 2;
  float acc[4][4] = {{0.f}};
  const float* ap = A + (size_t)(i0 + lrow) * D_SEM + lcol;
  const float* wp = T + (size_t)(j0 + lrow) * D_SEM + lcol;
  for (int k0 = 0; k0 < D_SEM; k0 += 16) {
    float4 av = *(const float4*)(ap + k0);
    float4 wv = *(const float4*)(wp + k0);
    __syncthreads();
    As[lcol + 0][lrow] = av.x; As[lcol + 1][lrow] = av.y;
    As[lcol + 2][lrow] = av.z; As[lcol + 3][lrow] = av.w;
    Bs[lcol + 0][lrow] = wv.x; Bs[lcol + 1][lrow] = wv.y;
    Bs[lcol + 2][lrow] = wv.z; Bs[lcol + 3][lrow] = wv.w;
    __syncthreads();
#pragma unroll
    for (int kk = 0; kk < 16; kk++) {
      float a[4], b[4];
#pragma unroll
      for (int y = 0; y < 4; y++) a[y] = As[kk][ty * 4 + y];
#pragma unroll
      for (int x = 0; x < 4; x++) b[x] = Bs[kk][tx * 4 + x];
#pragma unroll
      for (int y = 0; y < 4; y++)
#pragma unroll
        for (int x = 0; x < 4; x++) acc[y][x] = fmaf(a[y], b[x], acc[y][x]);
    }
  }
#pragma unroll
  for (int y = 0; y < 4; y++)
#pragma unroll
    for (int x = 0; x < 4; x++)
      P[(size_t)(i0 + ty * 4 + y) * S_SLOTS + j0 + tx * 4 + x] = acc[y][x];
}

// ---------------------------------------------------------------------------
// init: copy traces0 -> out (working traces), n_g[s] = ||t_s||^2, reset state.
// ---------------------------------------------------------------------------
__global__ __launch_bounds__(256)
void init_kernel(const float* __restrict__ traces0, float* __restrict__ out,
                 float* __restrict__ n_g, int* __restrict__ state) {
  __shared__ float wsum[4];
  const int s = blockIdx.x, t = threadIdx.x;
  const int lane = t & 63, wave = t >> 6;
  float4 v = *(const float4*)(traces0 + (size_t)s * D_SEM + 4 * t);
  *(float4*)(out + (size_t)s * D_SEM + 4 * t) = v;
  float nn = v.x * v.x + v.y * v.y + v.z * v.z + v.w * v.w;
#pragma unroll
  for (int o = 32; o; o >>= 1) nn += __shfl_down(nn, o, 64);
  if (lane == 0) wsum[wave] = nn;
  __syncthreads();
  if (t == 0) n_g[s] = wsum[0] + wsum[1] + wsum[2] + wsum[3];
  if (s == 0 && t == 0) { state[0] = 0; state[1] = 0; }
}

// ---------------------------------------------------------------------------
// DPP wave64 min (f32): row_shr 1/2/4/8 then row_bcast15 (rows 1,3) and
// row_bcast31 (rows 2,3); lane 63 holds the wave min; readlane broadcasts.
// old = self, so masked/invalid lanes are harmless under fminf.
// ---------------------------------------------------------------------------
__device__ __forceinline__ float wave_min_f32(float x) {
  int xi = __float_as_int(x), y;
  y = __builtin_amdgcn_update_dpp(xi, xi, 0x111, 0xF, 0xF, false);  // row_shr:1
  x = fminf(x, __int_as_float(y)); xi = __float_as_int(x);
  y = __builtin_amdgcn_update_dpp(xi, xi, 0x112, 0xF, 0xF, false);  // row_shr:2
  x = fminf(x, __int_as_float(y)); xi = __float_as_int(x);
  y = __builtin_amdgcn_update_dpp(xi, xi, 0x114, 0xF, 0xF, false);  // row_shr:4
  x = fminf(x, __int_as_float(y)); xi = __float_as_int(x);
  y = __builtin_amdgcn_update_dpp(xi, xi, 0x118, 0xF, 0xF, false);  // row_shr:8
  x = fminf(x, __int_as_float(y)); xi = __float_as_int(x);
  y = __builtin_amdgcn_update_dpp(xi, xi, 0x142, 0xA, 0xF, false);  // row_bcast:15
  x = fminf(x, __int_as_float(y)); xi = __float_as_int(x);
  y = __builtin_amdgcn_update_dpp(xi, xi, 0x143, 0xC, 0xF, false);  // row_bcast:31
  x = fminf(x, __int_as_float(y)); xi = __float_as_int(x);
  return __int_as_float(__builtin_amdgcn_readlane(xi, 63));
}

// ---------------------------------------------------------------------------
// Sequential scan, one WG, 256 thr.  Thread t owns slots [16t,16t+16).
// P0 READ-ONLY; trace state as t_s = alpha_s*t_s0 + sum coeff_j*c_j (entry j
// owned by thread j).  ONE barrier/step:
//   pre-barrier : prefetches; scatter coeff_j*G[I+2][j] (coeffs S_{I-1}) into
//                 parity corr buffer (stride-17 swizzle, conflict-free);
//                 local argmin keys; DPP wave-min + ballot; partials write.
//   post-barrier: redundant decision; owner applies decision I's closed-form
//                 fix to corr[slot_I]; rotate window; entering row I+2 =
//                 alpha*raw + corr; zero own corr entries.
// corr + partials double-buffered by parity so one barrier suffices.
// ---------------------------------------------------------------------------
#define CORR_SZ 4352   // 4096 + 4096/16 (stride-17 swizzle)
#define SWZ(s) ((s) + ((s) >> 4))

__global__ __launch_bounds__(256, 1)
void scan_kernel(const float* __restrict__ P, const float* __restrict__ Gb,
                 const float* __restrict__ rewards, const float* __restrict__ n_g,
                 int* __restrict__ state, u64* __restrict__ decs) {
  __shared__ float corr0[CORR_SZ];
  __shared__ float corr1[CORR_SZ];
  __shared__ u64 partials[2][4];
  const int t = threadIdx.x;          // 0..255
  const int lane = t & 63, wave = t >> 6;
  const int s_base = t << 4;
  const int c_base = 17 * t;          // SWZ(s_base + k) == c_base + k

  int num = state[0];
  int ptr = state[1];

  for (int s = t; s < CORR_SZ; s += 256) { corr0[s] = 0.f; corr1[s] = 0.f; }

  // per-slot ||t_s||^2 in owner registers; +inf marks invalid
  float n_reg[16];
#pragma unroll
  for (int k = 0; k < 16; k += 4) {
    float4 nv = *(const float4*)(n_g + s_base + k);
    n_reg[k + 0] = (s_base + k + 0 < num) ? nv.x : __uint_as_float(0x7F800000u);
    n_reg[k + 1] = (s_base + k + 1 < num) ? nv.y : __uint_as_float(0x7F800000u);
    n_reg[k + 2] = (s_base + k + 2 < num) ? nv.z : __uint_as_float(0x7F800000u);
    n_reg[k + 3] = (s_base + k + 3 < num) ? nv.w : __uint_as_float(0x7F800000u);
  }
  float alpha_r[16];
#pragma unroll
  for (int k = 0; k < 16; k++) alpha_r[k] = 1.f;

  // window: p_cur = row i, p_n1 = row i+1 (both fully corrected)
  float p_cur[16], p_n1[16];
#pragma unroll
  for (int k = 0; k < 16; k += 4) {
    float4 v0 = *(const float4*)(P + s_base + k);                       // row 0
    float4 v1 = *(const float4*)(P + (size_t)S_SLOTS + s_base + k);     // row 1
    p_cur[k] = v0.x; p_cur[k + 1] = v0.y; p_cur[k + 2] = v0.z; p_cur[k + 3] = v0.w;
    p_n1[k]  = v1.x; p_n1[k + 1]  = v1.y; p_n1[k + 2]  = v1.z; p_n1[k + 3]  = v1.w;
  }

  // raw prefetch ping-pong: buffer A holds row 2 initially
  float p_raw_a[16], p_raw_b[16];
  float gc_a, gc_b;
  {
    const float* rp = P + (size_t)2 * S_SLOTS + s_base;
#pragma unroll
    for (int k = 0; k < 16; k += 4) {
      float4 v = *(const float4*)(rp + k);
      p_raw_a[k] = v.x; p_raw_a[k + 1] = v.y; p_raw_a[k + 2] = v.z; p_raw_a[k + 3] = v.w;
    }
    gc_a = Gb[(size_t)2 * B_ITEMS + t];
    gc_b = 0.f;
#pragma unroll
    for (int k = 0; k < 16; k++) p_raw_b[k] = 0.f;
  }

  float gi = Gb[0];          // G[i][i]
  float ri = rewards[0];
  float g1 = Gb[1];          // G[i][i+1]

  int my_cslot = -1; float my_coeff = 0.f;   // thread t's decision entry
  u32 my_slot = 0; float my_lr = 0.f;        // decision latch for decs[]

  __syncthreads();   // corr zero-init visible

#define OWNFIX(K, I) { const float nold = n_reg[K]; \
    if (upd) { const float pc = 0.5f * (nold + gi - d2b); \
      n_reg[K] = omr * omr * nold + 2.0f * lr * omr * pc + lr * lr * gi; \
      alpha_r[K] = __fmul_rn(alpha_r[K], omr); \
      if ((I) + 1 < B_ITEMS) p_n1[K] = fmaf(omr, p_n1[K], __fmul_rn(lr, g1)); \
      if ((I) + 2 < B_ITEMS) cv[K] = fmaf(omr, cv[K], __fmul_rn(lr, gf)); \
    } else { n_reg[K] = gi; alpha_r[K] = 0.f; \
      if ((I) + 1 < B_ITEMS) p_n1[K] = g1; \
      if ((I) + 2 < B_ITEMS) cv[K] = gf; } }

#define SCAN_STEP(I, CBUF, RAWC, GCC, RAWN, GCN) { \
    /* TOP: prefetches (latency hidden under reduce) */ \
    if ((I) + 3 < B_ITEMS) { \
      const float* rp = P + (size_t)((I) + 3) * S_SLOTS + s_base; \
      _Pragma("unroll") \
      for (int k = 0; k < 16; k += 4) { \
        float4 v = *(const float4*)(rp + k); \
        RAWN[k] = v.x; RAWN[k + 1] = v.y; RAWN[k + 2] = v.z; RAWN[k + 3] = v.w; \
      } \
      GCN = Gb[(size_t)((I) + 3) * B_ITEMS + t]; \
    } \
    float gi_n = 0.f, ri_n = 0.f, g1_n = 0.f, gf = 0.f; \
    if ((I) + 1 < B_ITEMS) { \
      gi_n = Gb[(size_t)((I) + 1) * B_ITEMS + (I) + 1]; \
      ri_n = rewards[(I) + 1]; \
      if ((I) + 2 < B_ITEMS) g1_n = Gb[(size_t)((I) + 1) * B_ITEMS + (I) + 2]; \
    } \
    if ((I) + 2 < B_ITEMS) gf = Gb[(size_t)(I) * B_ITEMS + (I) + 2]; \
    /* SCATTER: coeffs S_{I-1} applied to entering row I+2 */ \
    if ((I) + 2 < B_ITEMS && my_coeff != 0.f) \
      atomicAdd(&CBUF[SWZ(my_cslot)], __fmul_rn(my_coeff, GCC)); \
    /* KEYS: local argmin over 16 owned slots (tree) */ \
    u64 kk[16]; \
    _Pragma("unroll") \
    for (int k = 0; k < 16; k++) { \
      const float v = fmaf(-2.0f, p_cur[k], n_reg[k] + gi); \
      const float d2 = (v > 0.f) ? v : 0.f; \
      kk[k] = ((u64)__float_as_uint(d2) << 32) | (u32)(s_base + k); \
    } \
    _Pragma("unroll") \
    for (int st = 1; st < 16; st <<= 1) \
      _Pragma("unroll") \
      for (int k = 0; k < 16; k += 2 * st) \
        if (kk[k + st] < kk[k]) kk[k] = kk[k + st]; \
    const float d2loc = __uint_as_float((u32)(kk[0] >> 32)); \
    const u32 sloc = (u32)kk[0]; \
    /* wave min via DPP + ballot index resolve (exact first-min) */ \
    const float dmin = wave_min_f32(d2loc); \
    const u64 bmask = __ballot(d2loc == dmin); \
    const int bl = __ffsll((unsigned long long)bmask) - 1; \
    const u32 swave = (u32)__builtin_amdgcn_readlane((int)sloc, bl); \
    if (lane == 0) \
      partials[(I) & 1][wave] = ((u64)__float_as_uint(dmin) << 32) | swave; \
    asm volatile("s_waitcnt lgkmcnt(0)" ::: "memory"); \
    __builtin_amdgcn_s_barrier(); \
    __builtin_amdgcn_sched_barrier(0); \
    /* DEC: read partials + own corr (independent LDS reads overlap) */ \
    u64 bk = partials[(I) & 1][0]; \
    { u64 v = partials[(I) & 1][1]; if (v < bk) bk = v; \
      v = partials[(I) & 1][2]; if (v < bk) bk = v; \
      v = partials[(I) & 1][3]; if (v < bk) bk = v; } \
    float cv[16]; \
    if ((I) + 2 < B_ITEMS) { \
      _Pragma("unroll") \
      for (int k = 0; k < 16; k++) cv[k] = CBUF[c_base + k]; \
    } else { \
      _Pragma("unroll") \
      for (int k = 0; k < 16; k++) cv[k] = 0.f; \
    } \
    const float d2b = __uint_as_float((u32)(bk >> 32)); \
    const int nslot = (int)(u32)bk; \
    const bool upd = (num > 0) && (d2b < 4.0f); \
    const float lr = __fmul_rn(0.01f, __fadd_rn(1.0f, fabsf(ri))); \
    const int slot = upd ? nslot : ptr; \
    const float omr = 1.0f - lr; \
    if (!upd) { num = min(num + 1, S_SLOTS); ptr = (ptr + 1) & (S_SLOTS - 1); } \
    if ((I) == t) { my_slot = (u32)slot | (upd ? 0x80000000u : 0u); my_lr = lr; } \
    if (my_cslot == slot) my_coeff = upd ? __fmul_rn(my_coeff, omr) : 0.f; \
    if ((I) == t) { my_cslot = slot; my_coeff = upd ? lr : 1.f; } \
    /* owner: n/alpha recurrence + window fix (row I+1) + corr fix (row I+2) */ \
    if ((slot >> 4) == t) { \
      switch (slot & 15) { \
        case 0:  OWNFIX(0,  I) break; case 1:  OWNFIX(1,  I) break; \
        case 2:  OWNFIX(2,  I) break; case 3:  OWNFIX(3,  I) break; \
        case 4:  OWNFIX(4,  I) break; case 5:  OWNFIX(5,  I) break; \
        case 6:  OWNFIX(6,  I) break; case 7:  OWNFIX(7,  I) break; \
        case 8:  OWNFIX(8,  I) break; case 9:  OWNFIX(9,  I) break; \
        case 10: OWNFIX(10, I) break; case 11: OWNFIX(11, I) break; \
        case 12: OWNFIX(12, I) break; case 13: OWNFIX(13, I) break; \
        case 14: OWNFIX(14, I) break; default: OWNFIX(15, I) break; \
      } \
    } \
    /* rotate + enter row I+2 + zero own corr entries */ \
    _Pragma("unroll") \
    for (int k = 0; k < 16; k++) p_cur[k] = p_n1[k]; \
    if ((I) + 2 < B_ITEMS) { \
      _Pragma("unroll") \
      for (int k = 0; k < 16; k++) { \
        p_n1[k] = fmaf(alpha_r[k], RAWC[k], cv[k]); \
        CBUF[c_base + k] = 0.f; \
      } \
    } \
    gi = gi_n; ri = ri_n; g1 = g1_n; \
  }

  for (int i = 0; i < B_ITEMS; i += 2) {
    SCAN_STEP(i,     corr0, p_raw_a, gc_a, p_raw_b, gc_b)
    SCAN_STEP(i + 1, corr1, p_raw_b, gc_b, p_raw_a, gc_a)
  }
#undef SCAN_STEP
#undef OWNFIX

  if (t == 0) { state[0] = num; state[1] = ptr; }
  decs[t] = ((u64)__float_as_uint(my_lr) << 32) | (u64)my_slot;
}

// ---------------------------------------------------------------------------
// apply: materialize the block's trace mutations. WG j owns slot_j iff step j
// is the LAST step touching it. Composition: t = alpha*t_snap + sum beta_j c_j.
// Recomputes exact ||t||^2 -> n_g (bounds numeric drift to one block).
// ---------------------------------------------------------------------------
__global__ __launch_bounds__(256)
void apply_kernel(const float* __restrict__ content,  // block 256 x 1024
                  const u64* __restrict__ decs,       // 256 decisions
                  float* __restrict__ traces,         // = out
                  float* __restrict__ n_g) {
  __shared__ u32 aslot[B_ITEMS];
  __shared__ float alr[B_ITEMS];
  __shared__ float betas[B_ITEMS];
  __shared__ int notowner;
  __shared__ float wsum[4];
  const int t = threadIdx.x, j = blockIdx.x;
  const int lane = t & 63, wave = t >> 6;
  const u64 d = decs[t];
  aslot[t] = (u32)(d & 0xFFFFFFFFull);
  alr[t] = __uint_as_float((u32)(d >> 32));
  if (t == 0) notowner = 0;
  __syncthreads();
  const u32 myslot = aslot[j] & 0x7FFFFFFFu;
  if (t > j && (aslot[t] & 0x7FFFFFFFu) == myslot) notowner = 1;
  __syncthreads();
  if (notowner) return;

  float alpha = 1.f, beta = 0.f;
  for (int k = 0; k < B_ITEMS; k++) {
    const u32 a = aslot[k];
    if ((a & 0x7FFFFFFFu) == myslot) {
      const float lr = alr[k];
      if (a & 0x80000000u) {           // update
        const float om = 1.f - lr;
        alpha *= om; beta *= om;
        if (t == k) beta += lr;
      } else {                         // insert
        alpha = 0.f; beta = (t == k) ? 1.f : 0.f;
      }
    }
  }
  betas[t] = beta;
  __syncthreads();

  float4 v = *(const float4*)(traces + (size_t)myslot * D_SEM + 4 * t);
  v.x *= alpha; v.y *= alpha; v.z *= alpha; v.w *= alpha;
  for (int k = 0; k < B_ITEMS; k++) {
    if ((aslot[k] & 0x7FFFFFFFu) == myslot) {
      const float bk = betas[k];
      const float4 c = *(const float4*)(content + (size_t)k * D_SEM + 4 * t);
      v.x = fmaf(bk, c.x, v.x); v.y = fmaf(bk, c.y, v.y);
      v.z = fmaf(bk, c.z, v.z); v.w = fmaf(bk, c.w, v.w);
    }
  }
  *(float4*)(traces + (size_t)myslot * D_SEM + 4 * t) = v;
  float nn = v.x * v.x + v.y * v.y + v.z * v.z + v.w * v.w;
#pragma unroll
  for (int o = 32; o; o >>= 1) nn += __shfl_down(nn, o, 64);
  if (lane == 0) wsum[wave] = nn;
  __syncthreads();
  if (t == 0) n_g[myslot] = wsum[0] + wsum[1] + wsum[2] + wsum[3];
}

// ---------------------------------------------------------------------------
// finalize: parallel strengths replay via two-pass LDS histogram.
// Per slot: final strength = 1 + (#updates after last insert) if ever
// inserted, else strengths0 + #updates.  Then masked mean + scalars.
// ---------------------------------------------------------------------------
__global__ __launch_bounds__(256)
void finalize_kernel(const float* __restrict__ strengths0,
                     const u64* __restrict__ decs,
                     const int* __restrict__ state, float* __restrict__ out) {
  __shared__ int last_ins[S_SLOTS];
  __shared__ int cnt[S_SLOTS];
  __shared__ float wsum[4];
  const int t = threadIdx.x, lane = t & 63, wave = t >> 6;
  for (int s = t; s < S_SLOTS; s += 256) { last_ins[s] = -1; cnt[s] = 0; }
  __syncthreads();
  // pass 1: last insert index per slot
  for (int k = t; k < N_ITEMS; k += 256) {
    const u32 dd = (u32)(decs[k] & 0xFFFFFFFFull);
    if (!(dd & 0x80000000u)) atomicMax(&last_ins[(int)dd], k);
  }
  __syncthreads();
  // pass 2: count updates after the last insert
  for (int k = t; k < N_ITEMS; k += 256) {
    const u32 dd = (u32)(decs[k] & 0xFFFFFFFFull);
    const int slot = (int)(dd & 0x7FFFFFFFu);
    if ((dd & 0x80000000u) && k > last_ins[slot]) atomicAdd(&cnt[slot], 1);
  }
  __syncthreads();
  const int num = state[0];
  float* outs = out + (size_t)S_SLOTS * D_SEM;
  float lsum = 0.f;
  for (int s = t; s < S_SLOTS; s += 256) {
    const float base = (last_ins[s] >= 0) ? 1.f : strengths0[s];
    const float v = base + (float)cnt[s];
    outs[s] = v;
    if (s < num) lsum += v;
  }
#pragma unroll
  for (int o = 32; o; o >>= 1) lsum += __shfl_down(lsum, o, 64);
  if (lane == 0) wsum[wave] = lsum;
  __syncthreads();
  if (t == 0) {
    const float total = wsum[0] + wsum[1] + wsum[2] + wsum[3];
    float denom = (float)num;
    if (denom < 1.f) denom = 1.f;
    outs[S_SLOTS + 0] = (float)num;
    outs[S_SLOTS + 1] = (float)N_ITEMS;
    outs[S_SLOTS + 2] = (num > 0) ? (total / denom) : 0.f;
  }
}

// ---------------------------------------------------------------------------
extern "C" void kernel_launch(void* const* d_in, const int* in_sizes, int n_in,
                              void* d_out, int out_size, void* d_ws, size_t ws_size,
                              hipStream_t stream) {
  const float* states  = (const float*)d_in[0];
  const float* rewards = (const float*)d_in[1];
  const float* W       = (const float*)d_in[2];
  const float* bias    = (const float*)d_in[3];
  const float* traces0 = (const float*)d_in[4];
  const float* str0    = (const float*)d_in[5];
  float* out = (float*)d_out;   // traces live here (working + final)

  // ws layout (~24.5 MB): content chunk 16MB | P 4MB | Gram 4MB | n_g | decs | state
  char* p = (char*)d_ws;
  float* cbuf = (float*)p;                 p += (size_t)CHUNK_ITEMS * D_SEM * 4;
  float* P    = (float*)p;                 p += (size_t)B_ITEMS * S_SLOTS * 4;
  float* Gb   = (float*)p;                 p += (size_t)CHUNK_BLKS * B_ITEMS * B_ITEMS * 4;
  float* n_g  = (float*)p;                 p += (size_t)S_SLOTS * 4;
  u64*   decs = (u64*)p;                   p += (size_t)N_ITEMS * 8;
  int*   state = (int*)p;

  init_kernel<<<S_SLOTS, 256, 0, stream>>>(traces0, out, n_g, state);

  for (int c = 0; c < N_ITEMS / CHUNK_ITEMS; c++) {
    gemm_kernel<<<dim3(CHUNK_ITEMS / 64, D_SEM / 64), 256, 0, stream>>>(
        states + (size_t)c * CHUNK_ITEMS * D_STATE, W, bias, cbuf);
    gram_kernel<<<dim3(4, 4, CHUNK_BLKS), 256, 0, stream>>>(cbuf, Gb);
    for (int bb = 0; bb < CHUNK_BLKS; bb++) {
      const int b = c * CHUNK_BLKS + bb;
      const float* cblk = cbuf + (size_t)bb * B_ITEMS * D_SEM;
      const float* Gblk = Gb + (size_t)bb * B_ITEMS * B_ITEMS;
      pgemm_kernel<<<dim3(4, S_SLOTS / 64), 256, 0, stream>>>(cblk, out, P, state);
      scan_kernel<<<1, 256, 0, stream>>>(P, Gblk, rewards + (size_t)b * B_ITEMS,
                                         n_g, state, decs + (size_t)b * B_ITEMS);
      apply_kernel<<<B_ITEMS, 256, 0, stream>>>(cblk, decs + (size_t)b * B_ITEMS,
                                                out, n_g);
    }
  }
  finalize_kernel<<<1, 256, 0, stream>>>(str0, decs, state, out);
}